// Round 2
// baseline (123.139 us; speedup 1.0000x reference)
//
#include <hip/hip_runtime.h>
#include <math.h>

// Neural Additive Model: 256 per-feature MLPs 1->128->64->32->1 (ReLU), summed.
// B=8192, fp32 in/out.
//
// Exact rank-table decomposition: pre-relu h2[b,k] = x_b*Sw[r,k] + Sb[r,k],
// r = #(sorted layer-1 thresholds < x_b). Layer 3 on f16 MFMA 32x32x16
// (A=W3^T, B=h2), layer 4 reduced in-register + 1 shfl.
//
// Round 19: REMOVE OUTPUT ATOMICS. R18's software pipeline was null (no
// barrier in the round loop -> compiler had already hoisted the loads), so
// main is throughput-bound; the unmodeled cost is 2M lane-level atomic RMWs
// on out[], maximally contended (at round 0 all 256 feature-blocks of a
// quarter hit the SAME two cachelines -> ~4k serialized RMWs/line).
// Main now does plain coalesced stores of p+b4 into parts[f][b] (8 MB of ws
// after the tables); a tiny reduce_out kernel (32 blocks x 1024 thr, float4
// over b, 16-way f-split + LDS combine) writes out[b] = bias + sum_f parts.
// Kernel-boundary release/acquire covers cross-XCD visibility (same as the
// existing build->main ws handoff). Build drops the out-init.

#define NF   256
#define NH1  128
#define NH2  64
#define NH3  32
#define NB   8192

#define NRANK 129
#define ROW4  17                      // uint4 per table row (16 data + 1 pad)
#define ROWH  136                     // halfwords per row
#define TBLDW 8960                    // dword stride per feature in ws
#define PART_DW (NF * TBLDW)          // parts region offset (dwords) in ws

typedef float    f32x16 __attribute__((ext_vector_type(16)));
typedef unsigned u32x4  __attribute__((ext_vector_type(4)));
typedef _Float16 h16x2  __attribute__((ext_vector_type(2)));
typedef _Float16 h16x8  __attribute__((ext_vector_type(8)));

// h2 pair: relu(x*Sw + Sb) on 2 packed f16 channels -> one B-frag dword
__device__ __forceinline__ unsigned pkh2(unsigned sw, unsigned sb, h16x2 xh) {
    h16x2 r = __builtin_elementwise_fma(xh, __builtin_bit_cast(h16x2, sw),
                                            __builtin_bit_cast(h16x2, sb));
    h16x2 hz = {(_Float16)0.f, (_Float16)0.f};
    return __builtin_bit_cast(unsigned, __builtin_elementwise_max(r, hz));
}

// ---------------- build: one block (1024 thr) per feature; table -> ws ----------------
__global__ __launch_bounds__(1024) void build_tables(
    const float* __restrict__ W1, const float* __restrict__ b1,
    const float* __restrict__ W2, const float* __restrict__ b2,
    unsigned* __restrict__ ws)
{
    __shared__ u32x4 SP4[NRANK * ROW4];    // 35.1 KB packed f16 table
    __shared__ float rkey[NH1];            // raw thresholds
    __shared__ float skey[NH1];            // sorted thresholds
    __shared__ int   sidx[NH1];            // sorted payload (channel idx)
    __shared__ float w1s[NH1], b1s[NH1];
    __shared__ float Pbw[16][NH2], Pbb[16][NH2], Pdw[16][NH2], Pdb[16][NH2]; // 16 KB

    const int f = blockIdx.x;
    const int t = (int)threadIdx.x;
    _Float16* SPh = (_Float16*)SP4;

    const float* __restrict__ gw2 = W2 + (size_t)f * NH1 * NH2;
    if (t < NH1) {
        float w  = W1[f * NH1 + t];
        float bb = b1[f * NH1 + t];
        w1s[t] = w; b1s[t] = bb;
        rkey[t] = (w != 0.0f) ? (-bb / w) : INFINITY;   // w==0: never toggled
    }
    __syncthreads();

    // counting-rank sort: 128 threads, each ranks its key vs all 128 (broadcast
    // LDS reads), ties broken by index. 1 barrier instead of bitonic's 28.
    if (t < NH1) {
        const float my = rkey[t];
        int rk = 0;
        #pragma unroll 16
        for (int i = 0; i < NH1; ++i) {
            float ki = rkey[i];
            rk += (ki < my || (ki == my && i < t)) ? 1 : 0;
        }
        skey[rk] = my; sidx[rk] = t;
    }
    __syncthreads();

    // chunked scan: 1024 threads = (k = t&63) x (chunk c = t>>6, 8 j/ranks each)
    {
        const int k = t & 63, c = t >> 6;
        float bw = 0.0f, bbp = 0.0f, dw = 0.0f, db = 0.0f;
        #pragma unroll
        for (int i = 0; i < 8; ++i) {
            int j = c * 8 + i;    // rank-0 base: w<0 active; w==0&&b>0 const-on
            float w = w1s[j], bv = b1s[j], w2v = gw2[j * NH2 + k];
            if (w < 0.0f) { bw = fmaf(w, w2v, bw); bbp = fmaf(bv, w2v, bbp); }
            else if (w == 0.0f && bv > 0.0f) { bbp = fmaf(bv, w2v, bbp); }
            int jj = sidx[c * 8 + i];   // toggle-delta partial
            float ww = w1s[jj], bv2 = b1s[jj], w2x = gw2[jj * NH2 + k];
            float s = (ww > 0.0f) ? 1.0f : ((ww < 0.0f) ? -1.0f : 0.0f);
            dw = fmaf(s * ww,  w2x, dw);
            db = fmaf(s * bv2, w2x, db);
        }
        Pbw[c][k] = bw; Pbb[c][k] = bbp; Pdw[c][k] = dw; Pdb[c][k] = db;
    }
    __syncthreads();
    {
        const int k = t & 63, c = t >> 6;
        float accw = 0.0f;
        float accb = b2[f * NH2 + k];    // b2 seed (round-8 lesson)
        #pragma unroll
        for (int c2 = 0; c2 < 16; ++c2) { accw += Pbw[c2][k]; accb += Pbb[c2][k]; }
        for (int c2 = 0; c2 < c; ++c2) { accw += Pdw[c2][k]; accb += Pdb[c2][k]; }
        // layout per row: Sw halves [0..63], Sb halves [64..127], pad to 136
        if (c == 0) {
            SPh[k]      = (_Float16)accw;          // rank-0 row
            SPh[64 + k] = (_Float16)accb;
        }
        #pragma unroll
        for (int i = 0; i < 8; ++i) {
            int r = c * 8 + i;
            int j = sidx[r];                       // uniform per chunk -> broadcast
            float w = w1s[j], bv = b1s[j], w2v = gw2[j * NH2 + k];
            float s = (w > 0.0f) ? 1.0f : ((w < 0.0f) ? -1.0f : 0.0f);
            accw = fmaf(s * w,  w2v, accw);
            accb = fmaf(s * bv, w2v, accb);
            SPh[(r + 1) * ROWH + k]      = (_Float16)accw;
            SPh[(r + 1) * ROWH + 64 + k] = (_Float16)accb;
        }
    }
    __syncthreads();

    // coalesced copy-out: skey[128] then the table flat
    unsigned* __restrict__ wsf = ws + (size_t)f * TBLDW;
    if (t < NH1) wsf[t] = __float_as_uint(skey[t]);
    const u32x4* src = (const u32x4*)SP4;
    u32x4* dst = (u32x4*)(wsf + NH1);
    for (int i = t; i < NRANK * ROW4; i += 1024) dst[i] = src[i];
}

// ---------------- main: 512 thr, one block = (feature, batch quarter) ----------------
__global__ __launch_bounds__(512, 4) void nam_main(
    const float* __restrict__ x,      // [B][F], strided reads (L3 absorbs reuse)
    const float* __restrict__ W3, const float* __restrict__ b3,
    const float* __restrict__ W4, const float* __restrict__ b4,
    unsigned* __restrict__ ws)
{
    __shared__ u32x4 SP4[NRANK * ROW4];    // 35.1 KB packed f16 table
    __shared__ float tkey[NH1];

    const int f  = blockIdx.x >> 2;        // feature
    const int qt = blockIdx.x & 3;         // batch quarter (2048 elems)
    const int t  = (int)threadIdx.x;

    // stage table from ws (L3-served; 9 MB total, read 4x)
    const unsigned* __restrict__ wsf = ws + (size_t)f * TBLDW;
    if (t < NH1) tkey[t] = __uint_as_float(wsf[t]);
    {
        const u32x4* src = (const u32x4*)(wsf + NH1);
        #pragma unroll 2
        for (int i = t; i < NRANK * ROW4; i += 512) SP4[i] = src[i];
    }
    __syncthreads();

    // ======== MFMA main loop, 32x32x16 f16 (A = W3^T, B = h2) ========
    const int lane = t & 63, wv = t >> 6;   // 8 waves
    const int n = lane & 31, q2 = lane >> 5;

    // A-frags: A[m=lane&31][k=(lane>>5)*8+j] = W3[kk][ch=m]; 4 K-tiles of 16
    const float* __restrict__ w3g = W3 + f * NH2 * NH3;
    h16x8 A0, A1, A2, A3;
    #pragma unroll
    for (int j = 0; j < 8; ++j) {
        int kk = q2 * 8 + j;
        A0[j] = (_Float16)w3g[kk * NH3 + n];
        A1[j] = (_Float16)w3g[(kk + 16) * NH3 + n];
        A2[j] = (_Float16)w3g[(kk + 32) * NH3 + n];
        A3[j] = (_Float16)w3g[(kk + 48) * NH3 + n];
    }
    // per-lane channel constants for the 16 C/D rows:
    // row(reg) = (reg&3) + 8*(reg>>2) + 4*q2
    // bacc seeds the first MFMA's C operand directly (D!=C: no per-round movs)
    f32x16 bacc;
    float w4r[16];
    #pragma unroll
    for (int reg = 0; reg < 16; ++reg) {
        int row = (reg & 3) + 8 * (reg >> 2) + 4 * q2;
        bacc[reg] = b3[f * NH3 + row];
        w4r[reg]  = W4[f * NH3 + row];
    }
    const float b4f = b4[f];
    float* __restrict__ parts = (float*)(ws + PART_DW) + (size_t)f * NB;
    // register-tree search levels s=64/32/16 (7 thresholds)
    const float t63 = tkey[63], t31 = tkey[31], t95 = tkey[95];
    const float t15 = tkey[15], t47 = tkey[47], t79 = tkey[79], t111 = tkey[111];

    // rank = #(tkey < q): 3 register levels + 4 LDS levels
    auto rankof = [&](float q) -> int {
        int rr = (t63 < q) ? 64 : 0;
        {
            float l1 = (rr & 64) ? t95 : t31;
            if (l1 < q) rr += 32;
            float m0 = (rr & 64) ? t79  : t15;
            float m1 = (rr & 64) ? t111 : t47;
            float l2 = (rr & 32) ? m1 : m0;
            if (l2 < q) rr += 16;
        }
        #pragma unroll
        for (int s = 8; s > 0; s >>= 1)
            if (tkey[rr + s - 1] < q) rr += s;
        return rr;
    };

    // software pipeline prologue: round 0's x and rank
    const int base0 = qt * 2048 + wv * 32;  // this wave's first 32-elem tile
    float xv = x[(size_t)(base0 + n) * NF + f];
    int r = rankof(xv);

    #pragma unroll 1
    for (int round = 0; round < 8; ++round) {
        const int base = base0 + round * 256;

        // issue next round's x-load immediately (clamp wraps the last round's
        // prefetch to a harmless in-range row; result unused then)
        const int nidx = (base + 256 + n) & (NB - 1);
        const float xnext = x[(size_t)nidx * NF + f];

        // gather lane's pair-dwords for its column n, row r:
        // Sw uint4 tiles T*2+q2 (T=0..3), Sb at +8
        const int ro = r * ROW4;
        u32x4 SW0 = SP4[ro + q2],      SW1 = SP4[ro + 2 + q2];
        u32x4 SW2 = SP4[ro + 4 + q2],  SW3 = SP4[ro + 6 + q2];
        u32x4 SB0 = SP4[ro + 8 + q2],  SB1 = SP4[ro + 10 + q2];
        u32x4 SB2 = SP4[ro + 12 + q2], SB3 = SP4[ro + 14 + q2];

        // B-frags: one pk_fma + pk_max per 2 channels
        const h16x2 xh = {(_Float16)xv, (_Float16)xv};
        u32x4 d0, d1, d2, d3;
        d0.x = pkh2(SW0.x, SB0.x, xh); d0.y = pkh2(SW0.y, SB0.y, xh);
        d0.z = pkh2(SW0.z, SB0.z, xh); d0.w = pkh2(SW0.w, SB0.w, xh);
        d1.x = pkh2(SW1.x, SB1.x, xh); d1.y = pkh2(SW1.y, SB1.y, xh);
        d1.z = pkh2(SW1.z, SB1.z, xh); d1.w = pkh2(SW1.w, SB1.w, xh);
        d2.x = pkh2(SW2.x, SB2.x, xh); d2.y = pkh2(SW2.y, SB2.y, xh);
        d2.z = pkh2(SW2.z, SB2.z, xh); d2.w = pkh2(SW2.w, SB2.w, xh);
        d3.x = pkh2(SW3.x, SB3.x, xh); d3.y = pkh2(SW3.y, SB3.y, xh);
        d3.z = pkh2(SW3.z, SB3.z, xh); d3.w = pkh2(SW3.w, SB3.w, xh);
        h16x8 B0 = __builtin_bit_cast(h16x8, d0);
        h16x8 B1 = __builtin_bit_cast(h16x8, d1);
        h16x8 B2 = __builtin_bit_cast(h16x8, d2);
        h16x8 B3 = __builtin_bit_cast(h16x8, d3);

        // layer 3: D[ch][batch], fp32 acc seeded with b3 rows via C operand
        f32x16 acc = __builtin_amdgcn_mfma_f32_32x32x16_f16(A0, B0, bacc, 0, 0, 0);
        acc = __builtin_amdgcn_mfma_f32_32x32x16_f16(A1, B1, acc, 0, 0, 0);
        acc = __builtin_amdgcn_mfma_f32_32x32x16_f16(A2, B2, acc, 0, 0, 0);
        acc = __builtin_amdgcn_mfma_f32_32x32x16_f16(A3, B3, acc, 0, 0, 0);

        // next round's rank walk (LDS pipe) in the shadow of MFMA + reduce
        const int rnext = rankof(xnext);

        // layer 4: reduce lane's own 16 channel rows, 1 shfl over q2,
        // then a PLAIN coalesced store into parts[f][base+lane] (no atomics)
        float p = 0.0f;
        #pragma unroll
        for (int reg = 0; reg < 16; ++reg)
            p = fmaf(fmaxf(acc[reg], 0.0f), w4r[reg], p);
        p += __shfl_xor(p, 32);
        if (lane < 32) parts[base + lane] = p + b4f;

        xv = xnext; r = rnext;
    }
}

// ---------------- reduce: out[b] = bias + sum_f parts[f][b] ----------------
__global__ __launch_bounds__(1024) void reduce_out(
    const float4* __restrict__ parts4,   // [NF][NB/4]
    const float* __restrict__ bias,
    float4* __restrict__ out4)           // [NB/4]
{
    __shared__ float4 red[16][64];
    const int t  = (int)threadIdx.x;
    const int bq = blockIdx.x * 64 + (t & 63);   // float4 index over batch
    const int fg = t >> 6;                       // f-group 0..15 (16 f each)

    float4 s = {0.f, 0.f, 0.f, 0.f};
    #pragma unroll
    for (int i = 0; i < 16; ++i) {
        const int f = fg * 16 + i;
        float4 v = parts4[(size_t)f * (NB / 4) + bq];
        s.x += v.x; s.y += v.y; s.z += v.z; s.w += v.w;
    }
    red[fg][t & 63] = s;
    __syncthreads();
    if (t < 64) {
        float4 a = red[0][t];
        #pragma unroll
        for (int g = 1; g < 16; ++g) {
            float4 v = red[g][t];
            a.x += v.x; a.y += v.y; a.z += v.z; a.w += v.w;
        }
        const float bb = bias[0];
        a.x += bb; a.y += bb; a.z += bb; a.w += bb;
        out4[bq] = a;
    }
}

extern "C" void kernel_launch(void* const* d_in, const int* in_sizes, int n_in,
                              void* d_out, int out_size, void* d_ws, size_t ws_size,
                              hipStream_t stream) {
    const float* x    = (const float*)d_in[0];
    const float* W1   = (const float*)d_in[1];
    const float* b1   = (const float*)d_in[2];
    const float* W2   = (const float*)d_in[3];
    const float* b2   = (const float*)d_in[4];
    const float* W3   = (const float*)d_in[5];
    const float* b3   = (const float*)d_in[6];
    const float* W4   = (const float*)d_in[7];
    const float* b4   = (const float*)d_in[8];
    const float* bias = (const float*)d_in[9];
    float* out   = (float*)d_out;
    unsigned* ws = (unsigned*)d_ws;   // needs NF*TBLDW*4 + NF*NB*4 = 17.6 MB

    // build: 1 block/feature; tables -> ws
    build_tables<<<NF, 1024, 0, stream>>>(W1, b1, W2, b2, ws);
    // main: grid 1024 = (feature, batch quarter); 35.6 KB LDS -> 4 blocks/CU
    nam_main<<<NF * 4, 512, 0, stream>>>(x, W3, b3, W4, b4, ws);
    // reduce: 32 blocks x 1024 thr; float4 over b, 16-way f-split + LDS combine
    reduce_out<<<NB / 256, 1024, 0, stream>>>(
        (const float4*)(ws + PART_DW), bias, (float4*)out);
}

// Round 3
// 120.086 us; speedup vs baseline: 1.0254x; 1.0254x over previous
//
#include <hip/hip_runtime.h>
#include <math.h>

// Neural Additive Model: 256 per-feature MLPs 1->128->64->32->1 (ReLU), summed.
// B=8192, fp32 in/out.
//
// Exact rank-table decomposition: pre-relu h2[b,k] = x_b*Sw[r,k] + Sb[r,k],
// r = #(sorted layer-1 thresholds < x_b). Layer 3 on f16 MFMA 32x32x16
// (A=W3^T, B=h2), layer 4 reduced in-register + 1 shfl, 1 atomic/elem.
//
// Round 20: (a) REVERT R19's parts+reduce experiment -> R18 atomic epilogue
// (R19 measured +2us: atomics were never the bottleneck). (b) NEW: x is
// transposed to xT[f][b] inside build_tables (LDS-tiled 64x64, both sides
// coalesced, row-padded 65 -> conflict-free). nam_main's x load was the last
// scatter: 64 distinct 64B lines per wave-load (16x overfetch, ~128 MB of
// L3->L1 traffic, ~8K line transactions/CU of TA occupancy). Now it reads
// xT[f][base+n]: 128 B / wave, 2 lines. No extra dispatch (fused in build;
// 256 blocks x 2 tiles each, +17 KB LDS -> build ~70 KB, still 1 block/CU).

#define NF   256
#define NH1  128
#define NH2  64
#define NH3  32
#define NB   8192

#define NRANK 129
#define ROW4  17                      // uint4 per table row (16 data + 1 pad)
#define ROWH  136                     // halfwords per row
#define TBLDW 8960                    // dword stride per feature in ws
#define XT_DW (NF * TBLDW)            // xT region offset (dwords) in ws

typedef float    f32x16 __attribute__((ext_vector_type(16)));
typedef unsigned u32x4  __attribute__((ext_vector_type(4)));
typedef _Float16 h16x2  __attribute__((ext_vector_type(2)));
typedef _Float16 h16x8  __attribute__((ext_vector_type(8)));

// h2 pair: relu(x*Sw + Sb) on 2 packed f16 channels -> one B-frag dword
__device__ __forceinline__ unsigned pkh2(unsigned sw, unsigned sb, h16x2 xh) {
    h16x2 r = __builtin_elementwise_fma(xh, __builtin_bit_cast(h16x2, sw),
                                            __builtin_bit_cast(h16x2, sb));
    h16x2 hz = {(_Float16)0.f, (_Float16)0.f};
    return __builtin_bit_cast(unsigned, __builtin_elementwise_max(r, hz));
}

// ---------------- build: one block (1024 thr) per feature; table -> ws ----------------
// Also: out-init (atomics add onto bias) and the x -> xT transpose (2 tiles/block).
__global__ __launch_bounds__(1024) void build_tables(
    const float* __restrict__ x,
    const float* __restrict__ W1, const float* __restrict__ b1,
    const float* __restrict__ W2, const float* __restrict__ b2,
    const float* __restrict__ bias, float* __restrict__ out,
    unsigned* __restrict__ ws)
{
    __shared__ u32x4 SP4[NRANK * ROW4];    // 35.1 KB packed f16 table
    __shared__ float rkey[NH1];            // raw thresholds
    __shared__ float skey[NH1];            // sorted thresholds
    __shared__ int   sidx[NH1];            // sorted payload (channel idx)
    __shared__ float w1s[NH1], b1s[NH1];
    __shared__ float Pbw[16][NH2], Pbb[16][NH2], Pdw[16][NH2], Pdb[16][NH2]; // 16 KB
    __shared__ float xtile[64][65];        // 16.6 KB transpose tile (padded)

    const int f = blockIdx.x;
    const int t = (int)threadIdx.x;
    _Float16* SPh = (_Float16*)SP4;

    // fused out-init (out poisoned before every launch; atomics add onto bias)
    const int gid = f * 1024 + t;
    if (gid < NB) out[gid] = bias[0];

    const float* __restrict__ gw2 = W2 + (size_t)f * NH1 * NH2;
    if (t < NH1) {
        float w  = W1[f * NH1 + t];
        float bb = b1[f * NH1 + t];
        w1s[t] = w; b1s[t] = bb;
        rkey[t] = (w != 0.0f) ? (-bb / w) : INFINITY;   // w==0: never toggled
    }
    __syncthreads();

    // counting-rank sort: 128 threads, each ranks its key vs all 128 (broadcast
    // LDS reads), ties broken by index. 1 barrier.
    if (t < NH1) {
        const float my = rkey[t];
        int rk = 0;
        #pragma unroll 16
        for (int i = 0; i < NH1; ++i) {
            float ki = rkey[i];
            rk += (ki < my || (ki == my && i < t)) ? 1 : 0;
        }
        skey[rk] = my; sidx[rk] = t;
    }
    __syncthreads();

    // chunked scan: 1024 threads = (k = t&63) x (chunk c = t>>6, 8 j/ranks each)
    {
        const int k = t & 63, c = t >> 6;
        float bw = 0.0f, bbp = 0.0f, dw = 0.0f, db = 0.0f;
        #pragma unroll
        for (int i = 0; i < 8; ++i) {
            int j = c * 8 + i;    // rank-0 base: w<0 active; w==0&&b>0 const-on
            float w = w1s[j], bv = b1s[j], w2v = gw2[j * NH2 + k];
            if (w < 0.0f) { bw = fmaf(w, w2v, bw); bbp = fmaf(bv, w2v, bbp); }
            else if (w == 0.0f && bv > 0.0f) { bbp = fmaf(bv, w2v, bbp); }
            int jj = sidx[c * 8 + i];   // toggle-delta partial
            float ww = w1s[jj], bv2 = b1s[jj], w2x = gw2[jj * NH2 + k];
            float s = (ww > 0.0f) ? 1.0f : ((ww < 0.0f) ? -1.0f : 0.0f);
            dw = fmaf(s * ww,  w2x, dw);
            db = fmaf(s * bv2, w2x, db);
        }
        Pbw[c][k] = bw; Pbb[c][k] = bbp; Pdw[c][k] = dw; Pdb[c][k] = db;
    }
    __syncthreads();
    {
        const int k = t & 63, c = t >> 6;
        float accw = 0.0f;
        float accb = b2[f * NH2 + k];    // b2 seed (round-8 lesson)
        #pragma unroll
        for (int c2 = 0; c2 < 16; ++c2) { accw += Pbw[c2][k]; accb += Pbb[c2][k]; }
        for (int c2 = 0; c2 < c; ++c2) { accw += Pdw[c2][k]; accb += Pdb[c2][k]; }
        // layout per row: Sw halves [0..63], Sb halves [64..127], pad to 136
        if (c == 0) {
            SPh[k]      = (_Float16)accw;          // rank-0 row
            SPh[64 + k] = (_Float16)accb;
        }
        #pragma unroll
        for (int i = 0; i < 8; ++i) {
            int r = c * 8 + i;
            int j = sidx[r];                       // uniform per chunk -> broadcast
            float w = w1s[j], bv = b1s[j], w2v = gw2[j * NH2 + k];
            float s = (w > 0.0f) ? 1.0f : ((w < 0.0f) ? -1.0f : 0.0f);
            accw = fmaf(s * w,  w2v, accw);
            accb = fmaf(s * bv, w2v, accb);
            SPh[(r + 1) * ROWH + k]      = (_Float16)accw;
            SPh[(r + 1) * ROWH + 64 + k] = (_Float16)accb;
        }
    }
    __syncthreads();

    // coalesced copy-out: skey[128] then the table flat
    unsigned* __restrict__ wsf = ws + (size_t)f * TBLDW;
    if (t < NH1) wsf[t] = __float_as_uint(skey[t]);
    const u32x4* src = (const u32x4*)SP4;
    u32x4* dst = (u32x4*)(wsf + NH1);
    for (int i = t; i < NRANK * ROW4; i += 1024) dst[i] = src[i];

    // ---- x -> xT transpose: 2 tiles of 64x64 per block, both sides coalesced
    // tiles: T = f*2 + tt; bt = T>>2 (batch tile 0..127), ft = T&3 (feat tile)
    float* __restrict__ xt = (float*)(ws + XT_DW);
    #pragma unroll 1
    for (int tt = 0; tt < 2; ++tt) {
        const int T  = f * 2 + tt;
        const int bt = T >> 2, ft = T & 3;
        __syncthreads();
        #pragma unroll
        for (int it = 0; it < 4; ++it) {
            int idx = t + it * 1024;          // 4096 elems
            int rr = idx >> 6, cc = idx & 63; // read x[bt*64+rr][ft*64+cc]
            xtile[rr][cc] = x[(size_t)(bt * 64 + rr) * NF + ft * 64 + cc];
        }
        __syncthreads();
        #pragma unroll
        for (int it = 0; it < 4; ++it) {
            int idx = t + it * 1024;
            int cc = idx >> 6, rr = idx & 63; // write xT[ft*64+cc][bt*64+rr]
            xt[(size_t)(ft * 64 + cc) * NB + bt * 64 + rr] = xtile[rr][cc];
        }
    }
}

// ---------------- main: 512 thr, one block = (feature, batch quarter) ----------------
__global__ __launch_bounds__(512, 4) void nam_main(
    const float* __restrict__ W3, const float* __restrict__ b3,
    const float* __restrict__ W4, const float* __restrict__ b4,
    const unsigned* __restrict__ ws,
    float* __restrict__ out)
{
    __shared__ u32x4 SP4[NRANK * ROW4];    // 35.1 KB packed f16 table
    __shared__ float tkey[NH1];

    const int f  = blockIdx.x >> 2;        // feature
    const int qt = blockIdx.x & 3;         // batch quarter (2048 elems)
    const int t  = (int)threadIdx.x;

    // stage table from ws (L3-served; 9 MB total, read 4x)
    const unsigned* __restrict__ wsf = ws + (size_t)f * TBLDW;
    if (t < NH1) tkey[t] = __uint_as_float(wsf[t]);
    {
        const u32x4* src = (const u32x4*)(wsf + NH1);
        #pragma unroll 2
        for (int i = t; i < NRANK * ROW4; i += 512) SP4[i] = src[i];
    }
    __syncthreads();

    // ======== MFMA main loop, 32x32x16 f16 (A = W3^T, B = h2) ========
    const int lane = t & 63, wv = t >> 6;   // 8 waves
    const int n = lane & 31, q2 = lane >> 5;

    // A-frags: A[m=lane&31][k=(lane>>5)*8+j] = W3[kk][ch=m]; 4 K-tiles of 16
    const float* __restrict__ w3g = W3 + f * NH2 * NH3;
    h16x8 A0, A1, A2, A3;
    #pragma unroll
    for (int j = 0; j < 8; ++j) {
        int kk = q2 * 8 + j;
        A0[j] = (_Float16)w3g[kk * NH3 + n];
        A1[j] = (_Float16)w3g[(kk + 16) * NH3 + n];
        A2[j] = (_Float16)w3g[(kk + 32) * NH3 + n];
        A3[j] = (_Float16)w3g[(kk + 48) * NH3 + n];
    }
    // per-lane channel constants for the 16 C/D rows:
    // row(reg) = (reg&3) + 8*(reg>>2) + 4*q2
    // bacc seeds the first MFMA's C operand directly (D!=C: no per-round movs)
    f32x16 bacc;
    float w4r[16];
    #pragma unroll
    for (int reg = 0; reg < 16; ++reg) {
        int row = (reg & 3) + 8 * (reg >> 2) + 4 * q2;
        bacc[reg] = b3[f * NH3 + row];
        w4r[reg]  = W4[f * NH3 + row];
    }
    const float b4f = b4[f];
    // coalesced x: this feature's row of xT
    const float* __restrict__ xrow = (const float*)(ws + XT_DW) + (size_t)f * NB;
    // register-tree search levels s=64/32/16 (7 thresholds)
    const float t63 = tkey[63], t31 = tkey[31], t95 = tkey[95];
    const float t15 = tkey[15], t47 = tkey[47], t79 = tkey[79], t111 = tkey[111];

    // rank = #(tkey < q): 3 register levels + 4 LDS levels
    auto rankof = [&](float q) -> int {
        int rr = (t63 < q) ? 64 : 0;
        {
            float l1 = (rr & 64) ? t95 : t31;
            if (l1 < q) rr += 32;
            float m0 = (rr & 64) ? t79  : t15;
            float m1 = (rr & 64) ? t111 : t47;
            float l2 = (rr & 32) ? m1 : m0;
            if (l2 < q) rr += 16;
        }
        #pragma unroll
        for (int s = 8; s > 0; s >>= 1)
            if (tkey[rr + s - 1] < q) rr += s;
        return rr;
    };

    // software pipeline prologue: round 0's x and rank
    const int base0 = qt * 2048 + wv * 32;  // this wave's first 32-elem tile
    float xv = xrow[base0 + n];
    int r = rankof(xv);

    #pragma unroll 1
    for (int round = 0; round < 8; ++round) {
        const int base = base0 + round * 256;

        // issue next round's x-load immediately (wrap keeps the last round's
        // prefetch in-range; result unused then)
        const float xnext = xrow[(base + 256 + n) & (NB - 1)];

        // gather lane's pair-dwords for its column n, row r:
        // Sw uint4 tiles T*2+q2 (T=0..3), Sb at +8
        const int ro = r * ROW4;
        u32x4 SW0 = SP4[ro + q2],      SW1 = SP4[ro + 2 + q2];
        u32x4 SW2 = SP4[ro + 4 + q2],  SW3 = SP4[ro + 6 + q2];
        u32x4 SB0 = SP4[ro + 8 + q2],  SB1 = SP4[ro + 10 + q2];
        u32x4 SB2 = SP4[ro + 12 + q2], SB3 = SP4[ro + 14 + q2];

        // B-frags: one pk_fma + pk_max per 2 channels
        const h16x2 xh = {(_Float16)xv, (_Float16)xv};
        u32x4 d0, d1, d2, d3;
        d0.x = pkh2(SW0.x, SB0.x, xh); d0.y = pkh2(SW0.y, SB0.y, xh);
        d0.z = pkh2(SW0.z, SB0.z, xh); d0.w = pkh2(SW0.w, SB0.w, xh);
        d1.x = pkh2(SW1.x, SB1.x, xh); d1.y = pkh2(SW1.y, SB1.y, xh);
        d1.z = pkh2(SW1.z, SB1.z, xh); d1.w = pkh2(SW1.w, SB1.w, xh);
        d2.x = pkh2(SW2.x, SB2.x, xh); d2.y = pkh2(SW2.y, SB2.y, xh);
        d2.z = pkh2(SW2.z, SB2.z, xh); d2.w = pkh2(SW2.w, SB2.w, xh);
        d3.x = pkh2(SW3.x, SB3.x, xh); d3.y = pkh2(SW3.y, SB3.y, xh);
        d3.z = pkh2(SW3.z, SB3.z, xh); d3.w = pkh2(SW3.w, SB3.w, xh);
        h16x8 B0 = __builtin_bit_cast(h16x8, d0);
        h16x8 B1 = __builtin_bit_cast(h16x8, d1);
        h16x8 B2 = __builtin_bit_cast(h16x8, d2);
        h16x8 B3 = __builtin_bit_cast(h16x8, d3);

        // layer 3: D[ch][batch], fp32 acc seeded with b3 rows via C operand
        f32x16 acc = __builtin_amdgcn_mfma_f32_32x32x16_f16(A0, B0, bacc, 0, 0, 0);
        acc = __builtin_amdgcn_mfma_f32_32x32x16_f16(A1, B1, acc, 0, 0, 0);
        acc = __builtin_amdgcn_mfma_f32_32x32x16_f16(A2, B2, acc, 0, 0, 0);
        acc = __builtin_amdgcn_mfma_f32_32x32x16_f16(A3, B3, acc, 0, 0, 0);

        // next round's rank walk (LDS pipe) in the shadow of MFMA + reduce
        const int rnext = rankof(xnext);

        // layer 4: reduce lane's own 16 channel rows, 1 shfl over q2, 1 atomic
        float p = 0.0f;
        #pragma unroll
        for (int reg = 0; reg < 16; ++reg)
            p = fmaf(fmaxf(acc[reg], 0.0f), w4r[reg], p);
        p += __shfl_xor(p, 32);
        if (lane < 32) atomicAdd(&out[base + lane], p + b4f);

        xv = xnext; r = rnext;
    }
}

extern "C" void kernel_launch(void* const* d_in, const int* in_sizes, int n_in,
                              void* d_out, int out_size, void* d_ws, size_t ws_size,
                              hipStream_t stream) {
    const float* x    = (const float*)d_in[0];
    const float* W1   = (const float*)d_in[1];
    const float* b1   = (const float*)d_in[2];
    const float* W2   = (const float*)d_in[3];
    const float* b2   = (const float*)d_in[4];
    const float* W3   = (const float*)d_in[5];
    const float* b3   = (const float*)d_in[6];
    const float* W4   = (const float*)d_in[7];
    const float* b4   = (const float*)d_in[8];
    const float* bias = (const float*)d_in[9];
    float* out   = (float*)d_out;
    unsigned* ws = (unsigned*)d_ws;   // needs NF*TBLDW*4 + NF*NB*4 = 17.6 MB

    // build: 1 block/feature; tables + out-init + x->xT transpose
    build_tables<<<NF, 1024, 0, stream>>>(x, W1, b1, W2, b2, bias, out, ws);
    // main: grid 1024 = (feature, batch quarter); 35.6 KB LDS -> 4 blocks/CU
    nam_main<<<NF * 4, 512, 0, stream>>>(W3, b3, W4, b4, ws, out);
}

// Round 4
// 111.686 us; speedup vs baseline: 1.1025x; 1.0752x over previous
//
#include <hip/hip_runtime.h>
#include <math.h>

// Neural Additive Model: 256 per-feature MLPs 1->128->64->32->1 (ReLU), summed.
// B=8192, fp32 in/out.
//
// Exact rank-table decomposition: pre-relu h2[b,k] = x_b*Sw[r,k] + Sb[r,k],
// r = #(sorted layer-1 thresholds < x_b). Layer 3 on f16 MFMA 32x32x16
// (A=W3^T, B=h2), layer 4 reduced in-register + 1 shfl, 1 atomic/elem.
//
// Round 21: FUSE build+main into one kernel. R17-R20 bracket the controllable
// budget at ~30us (two ~43us harness poison fills dominate dur_us); the last
// untouched fat is the ws table round-trip: build wrote 9 MB of tables, main
// re-read 36 MB (4 blocks/feature staged the same table) in a serialized L3
// burst at launch. Tables are per-feature-private, so one 1024-thr block per
// feature now builds its table in LDS and immediately runs the batch loop
// (16 waves x 16 rounds x 512 batches) against the resident table -- the
// 45 MB round-trip and both staging barriers vanish. xT (the only
// cross-feature data) is produced by a small standalone transpose kernel
// (512 tiles of 64x64, LDS-padded, both sides coalesced) that also fuses the
// out-init. Round order rotated by f&15 so features don't hammer the same
// out[] lines in lockstep. ws now holds only xT (8 MB).

#define NF   256
#define NH1  128
#define NH2  64
#define NH3  32
#define NB   8192

#define NRANK 129
#define ROW4  17                      // uint4 per table row (16 data + 1 pad)
#define ROWH  136                     // halfwords per row

typedef float    f32x16 __attribute__((ext_vector_type(16)));
typedef unsigned u32x4  __attribute__((ext_vector_type(4)));
typedef _Float16 h16x2  __attribute__((ext_vector_type(2)));
typedef _Float16 h16x8  __attribute__((ext_vector_type(8)));

// h2 pair: relu(x*Sw + Sb) on 2 packed f16 channels -> one B-frag dword
__device__ __forceinline__ unsigned pkh2(unsigned sw, unsigned sb, h16x2 xh) {
    h16x2 r = __builtin_elementwise_fma(xh, __builtin_bit_cast(h16x2, sw),
                                            __builtin_bit_cast(h16x2, sb));
    h16x2 hz = {(_Float16)0.f, (_Float16)0.f};
    return __builtin_bit_cast(unsigned, __builtin_elementwise_max(r, hz));
}

// ---------------- transpose: x[B][F] -> xT[F][B] in ws; fuses out-init ----------------
__global__ __launch_bounds__(1024) void transpose_x(
    const float* __restrict__ x, const float* __restrict__ bias,
    float* __restrict__ out, float* __restrict__ xt)
{
    __shared__ float xtile[64][65];        // padded -> conflict-free
    const int t = (int)threadIdx.x;
    const int T = blockIdx.x;              // 0..511
    const int bt = T >> 2, ft = T & 3;     // batch tile 0..127, feat tile 0..3

    if (T < 8) out[T * 1024 + t] = bias[0];   // out poisoned each launch

    #pragma unroll
    for (int it = 0; it < 4; ++it) {
        int idx = t + it * 1024;               // 4096 elems per tile
        int rr = idx >> 6, cc = idx & 63;      // read x[bt*64+rr][ft*64+cc]
        xtile[rr][cc] = x[(size_t)(bt * 64 + rr) * NF + ft * 64 + cc];
    }
    __syncthreads();
    #pragma unroll
    for (int it = 0; it < 4; ++it) {
        int idx = t + it * 1024;
        int cc = idx >> 6, rr = idx & 63;      // write xT[ft*64+cc][bt*64+rr]
        xt[(size_t)(ft * 64 + cc) * NB + bt * 64 + rr] = xtile[rr][cc];
    }
}

// ---------------- fused: one block (1024 thr) per feature ----------------
// Phase 1 builds the rank table in LDS (sort + chunked scan); phase 2 runs
// the MFMA batch loop (16 waves x 16 rounds x 512 batches) on the resident
// table. No table ever touches global memory.
__global__ __launch_bounds__(1024) void nam_fused(
    const float* __restrict__ W1, const float* __restrict__ b1,
    const float* __restrict__ W2, const float* __restrict__ b2,
    const float* __restrict__ W3, const float* __restrict__ b3,
    const float* __restrict__ W4, const float* __restrict__ b4,
    const float* __restrict__ xt,
    float* __restrict__ out)
{
    __shared__ u32x4 SP4[NRANK * ROW4];    // 35.1 KB packed f16 table
    __shared__ float rkey[NH1];            // raw thresholds
    __shared__ float skey[NH1];            // sorted thresholds (main reads too)
    __shared__ int   sidx[NH1];            // sorted payload (channel idx)
    __shared__ float w1s[NH1], b1s[NH1];
    __shared__ float Pbw[16][NH2], Pbb[16][NH2], Pdw[16][NH2], Pdb[16][NH2]; // 16 KB

    const int f = blockIdx.x;
    const int t = (int)threadIdx.x;
    _Float16* SPh = (_Float16*)SP4;

    // ======== phase 1: build table (identical math to R20 build) ========
    const float* __restrict__ gw2 = W2 + (size_t)f * NH1 * NH2;
    if (t < NH1) {
        float w  = W1[f * NH1 + t];
        float bb = b1[f * NH1 + t];
        w1s[t] = w; b1s[t] = bb;
        rkey[t] = (w != 0.0f) ? (-bb / w) : INFINITY;   // w==0: never toggled
    }
    __syncthreads();

    // counting-rank sort: 128 threads, each ranks its key vs all 128
    if (t < NH1) {
        const float my = rkey[t];
        int rk = 0;
        #pragma unroll 16
        for (int i = 0; i < NH1; ++i) {
            float ki = rkey[i];
            rk += (ki < my || (ki == my && i < t)) ? 1 : 0;
        }
        skey[rk] = my; sidx[rk] = t;
    }
    __syncthreads();

    // chunked scan: 1024 threads = (k = t&63) x (chunk c = t>>6, 8 j/ranks each)
    {
        const int k = t & 63, c = t >> 6;
        float bw = 0.0f, bbp = 0.0f, dw = 0.0f, db = 0.0f;
        #pragma unroll
        for (int i = 0; i < 8; ++i) {
            int j = c * 8 + i;    // rank-0 base: w<0 active; w==0&&b>0 const-on
            float w = w1s[j], bv = b1s[j], w2v = gw2[j * NH2 + k];
            if (w < 0.0f) { bw = fmaf(w, w2v, bw); bbp = fmaf(bv, w2v, bbp); }
            else if (w == 0.0f && bv > 0.0f) { bbp = fmaf(bv, w2v, bbp); }
            int jj = sidx[c * 8 + i];   // toggle-delta partial
            float ww = w1s[jj], bv2 = b1s[jj], w2x = gw2[jj * NH2 + k];
            float s = (ww > 0.0f) ? 1.0f : ((ww < 0.0f) ? -1.0f : 0.0f);
            dw = fmaf(s * ww,  w2x, dw);
            db = fmaf(s * bv2, w2x, db);
        }
        Pbw[c][k] = bw; Pbb[c][k] = bbp; Pdw[c][k] = dw; Pdb[c][k] = db;
    }
    __syncthreads();
    {
        const int k = t & 63, c = t >> 6;
        float accw = 0.0f;
        float accb = b2[f * NH2 + k];    // b2 seed (round-8 lesson)
        #pragma unroll
        for (int c2 = 0; c2 < 16; ++c2) { accw += Pbw[c2][k]; accb += Pbb[c2][k]; }
        for (int c2 = 0; c2 < c; ++c2) { accw += Pdw[c2][k]; accb += Pdb[c2][k]; }
        // layout per row: Sw halves [0..63], Sb halves [64..127], pad to 136
        if (c == 0) {
            SPh[k]      = (_Float16)accw;          // rank-0 row
            SPh[64 + k] = (_Float16)accb;
        }
        #pragma unroll
        for (int i = 0; i < 8; ++i) {
            int r = c * 8 + i;
            int j = sidx[r];                       // uniform per chunk -> broadcast
            float w = w1s[j], bv = b1s[j], w2v = gw2[j * NH2 + k];
            float s = (w > 0.0f) ? 1.0f : ((w < 0.0f) ? -1.0f : 0.0f);
            accw = fmaf(s * w,  w2v, accw);
            accb = fmaf(s * bv, w2v, accb);
            SPh[(r + 1) * ROWH + k]      = (_Float16)accw;
            SPh[(r + 1) * ROWH + 64 + k] = (_Float16)accb;
        }
    }
    __syncthreads();

    // ======== phase 2: MFMA batch loop on the resident table ========
    const int lane = t & 63, wv = t >> 6;   // 16 waves
    const int n = lane & 31, q2 = lane >> 5;

    // A-frags: A[m=lane&31][k=(lane>>5)*8+j] = W3[kk][ch=m]; 4 K-tiles of 16
    const float* __restrict__ w3g = W3 + f * NH2 * NH3;
    h16x8 A0, A1, A2, A3;
    #pragma unroll
    for (int j = 0; j < 8; ++j) {
        int kk = q2 * 8 + j;
        A0[j] = (_Float16)w3g[kk * NH3 + n];
        A1[j] = (_Float16)w3g[(kk + 16) * NH3 + n];
        A2[j] = (_Float16)w3g[(kk + 32) * NH3 + n];
        A3[j] = (_Float16)w3g[(kk + 48) * NH3 + n];
    }
    // per-lane channel constants for the 16 C/D rows:
    // row(reg) = (reg&3) + 8*(reg>>2) + 4*q2
    // bacc seeds the first MFMA's C operand directly (D!=C: no per-round movs)
    f32x16 bacc;
    float w4r[16];
    #pragma unroll
    for (int reg = 0; reg < 16; ++reg) {
        int row = (reg & 3) + 8 * (reg >> 2) + 4 * q2;
        bacc[reg] = b3[f * NH3 + row];
        w4r[reg]  = W4[f * NH3 + row];
    }
    const float b4f = b4[f];
    const float* __restrict__ xrow = xt + (size_t)f * NB;   // coalesced x
    // register-tree search levels s=64/32/16 (7 thresholds)
    const float t63 = skey[63], t31 = skey[31], t95 = skey[95];
    const float t15 = skey[15], t47 = skey[47], t79 = skey[79], t111 = skey[111];

    // rank = #(skey < q): 3 register levels + 4 LDS levels
    auto rankof = [&](float q) -> int {
        int rr = (t63 < q) ? 64 : 0;
        {
            float l1 = (rr & 64) ? t95 : t31;
            if (l1 < q) rr += 32;
            float m0 = (rr & 64) ? t79  : t15;
            float m1 = (rr & 64) ? t111 : t47;
            float l2 = (rr & 32) ? m1 : m0;
            if (l2 < q) rr += 16;
        }
        #pragma unroll
        for (int s = 8; s > 0; s >>= 1)
            if (skey[rr + s - 1] < q) rr += s;
        return rr;
    };

    // 16 rounds x 512 batches; round order rotated by f so features don't
    // hit the same out[] lines in lockstep. Software-pipelined x/rank.
    const int boff = wv * 32 + n;
    float xv = xrow[((0 + f) & 15) * 512 + boff];
    int r = rankof(xv);

    #pragma unroll 1
    for (int round = 0; round < 16; ++round) {
        const int base = (((round + f) & 15) * 16 + wv) * 32;
        // next round's x (last-round prefetch wraps to round 0's slot; unused)
        const float xnext = xrow[(((round + 1 + f) & 15) * 16 + wv) * 32 + n];

        // gather lane's pair-dwords for its column n, row r:
        // Sw uint4 tiles T*2+q2 (T=0..3), Sb at +8
        const int ro = r * ROW4;
        u32x4 SW0 = SP4[ro + q2],      SW1 = SP4[ro + 2 + q2];
        u32x4 SW2 = SP4[ro + 4 + q2],  SW3 = SP4[ro + 6 + q2];
        u32x4 SB0 = SP4[ro + 8 + q2],  SB1 = SP4[ro + 10 + q2];
        u32x4 SB2 = SP4[ro + 12 + q2], SB3 = SP4[ro + 14 + q2];

        // B-frags: one pk_fma + pk_max per 2 channels
        const h16x2 xh = {(_Float16)xv, (_Float16)xv};
        u32x4 d0, d1, d2, d3;
        d0.x = pkh2(SW0.x, SB0.x, xh); d0.y = pkh2(SW0.y, SB0.y, xh);
        d0.z = pkh2(SW0.z, SB0.z, xh); d0.w = pkh2(SW0.w, SB0.w, xh);
        d1.x = pkh2(SW1.x, SB1.x, xh); d1.y = pkh2(SW1.y, SB1.y, xh);
        d1.z = pkh2(SW1.z, SB1.z, xh); d1.w = pkh2(SW1.w, SB1.w, xh);
        d2.x = pkh2(SW2.x, SB2.x, xh); d2.y = pkh2(SW2.y, SB2.y, xh);
        d2.z = pkh2(SW2.z, SB2.z, xh); d2.w = pkh2(SW2.w, SB2.w, xh);
        d3.x = pkh2(SW3.x, SB3.x, xh); d3.y = pkh2(SW3.y, SB3.y, xh);
        d3.z = pkh2(SW3.z, SB3.z, xh); d3.w = pkh2(SW3.w, SB3.w, xh);
        h16x8 B0 = __builtin_bit_cast(h16x8, d0);
        h16x8 B1 = __builtin_bit_cast(h16x8, d1);
        h16x8 B2 = __builtin_bit_cast(h16x8, d2);
        h16x8 B3 = __builtin_bit_cast(h16x8, d3);

        // layer 3: D[ch][batch], fp32 acc seeded with b3 rows via C operand
        f32x16 acc = __builtin_amdgcn_mfma_f32_32x32x16_f16(A0, B0, bacc, 0, 0, 0);
        acc = __builtin_amdgcn_mfma_f32_32x32x16_f16(A1, B1, acc, 0, 0, 0);
        acc = __builtin_amdgcn_mfma_f32_32x32x16_f16(A2, B2, acc, 0, 0, 0);
        acc = __builtin_amdgcn_mfma_f32_32x32x16_f16(A3, B3, acc, 0, 0, 0);

        // next round's rank walk (LDS pipe) in the shadow of MFMA + reduce
        const int rnext = rankof(xnext);

        // layer 4: reduce lane's own 16 channel rows, 1 shfl over q2, 1 atomic
        float p = 0.0f;
        #pragma unroll
        for (int reg = 0; reg < 16; ++reg)
            p = fmaf(fmaxf(acc[reg], 0.0f), w4r[reg], p);
        p += __shfl_xor(p, 32);
        if (lane < 32) atomicAdd(&out[base + lane], p + b4f);

        xv = xnext; r = rnext;
    }
}

extern "C" void kernel_launch(void* const* d_in, const int* in_sizes, int n_in,
                              void* d_out, int out_size, void* d_ws, size_t ws_size,
                              hipStream_t stream) {
    const float* x    = (const float*)d_in[0];
    const float* W1   = (const float*)d_in[1];
    const float* b1   = (const float*)d_in[2];
    const float* W2   = (const float*)d_in[3];
    const float* b2   = (const float*)d_in[4];
    const float* W3   = (const float*)d_in[5];
    const float* b3   = (const float*)d_in[6];
    const float* W4   = (const float*)d_in[7];
    const float* b4   = (const float*)d_in[8];
    const float* bias = (const float*)d_in[9];
    float* out   = (float*)d_out;
    float* xtw   = (float*)d_ws;      // ws holds only xT: 8 MB

    // transpose (both sides coalesced) + out-init
    transpose_x<<<512, 1024, 0, stream>>>(x, bias, out, xtw);
    // fused: 1 block/feature = 1 block/CU; table lives and dies in LDS
    nam_fused<<<NF, 1024, 0, stream>>>(W1, b1, W2, b2, W3, b3, W4, b4, xtw, out);
}